// Round 1
// baseline (84.054 us; speedup 1.0000x reference)
//
#include <hip/hip_runtime.h>
#include <math.h>

// Problem constants (from reference): B=8, C=16, N=65536, K_CAND=10, K_TOP=4
#define BB 8
#define CC 16
#define NN 65536
#define KC 10
#define KT 4

// One point (b,n) is handled by a group of 4 consecutive lanes; each lane owns
// 4 channels. Sampled values live in registers (v[4][10]) so the weighted-sum
// pass after top-k selection needs no re-read from memory.
__global__ __launch_bounds__(256) void swg_kernel(
    const float* __restrict__ orig,   // [B][C][N]
    const float* __restrict__ samp,   // [B][C][N][KC]
    const float* __restrict__ w1,     // [2C]  (only w1[C:] needed)
    const float* __restrict__ w2,     // [2C]
    const float* __restrict__ b2p,    // scalar
    float* __restrict__ out)          // [B][C][N]
{
    const int t = blockIdx.x * blockDim.x + threadIdx.x;
    const int q = t & 3;              // channel-group within point (0..3)
    const int p = t >> 2;             // point id in [0, B*N)
    const int n = p & (NN - 1);       // N = 2^16
    const int b = p >> 16;

    const float b2 = b2p[0];

    float ws1[4], wo2[4], ws2[4];
#pragma unroll
    for (int cc = 0; cc < 4; ++cc) {
        const int c = q * 4 + cc;
        ws1[cc] = w1[CC + c];
        wo2[cc] = w2[c];
        ws2[cc] = w2[CC + c];
    }

    // ---- load: 4 channels x (1 orig + 10 sampled) ----
    float v[4][KC];
    float o[4];
#pragma unroll
    for (int cc = 0; cc < 4; ++cc) {
        const int c = q * 4 + cc;
        const size_t base = (size_t)(b * CC + c) * NN + n;
        o[cc] = orig[base];
        const float2* sp = (const float2*)(samp + base * KC);  // 40B, 8B-aligned
#pragma unroll
        for (int j = 0; j < 5; ++j) {
            const float2 x = sp[j];
            v[cc][2 * j]     = x.x;
            v[cc][2 * j + 1] = x.y;
        }
    }

    // ---- partial dots over this lane's 4 channels ----
    float s[KC], d2[KC];
    float dO = 0.f;
#pragma unroll
    for (int k = 0; k < KC; ++k) { s[k] = 0.f; d2[k] = 0.f; }
#pragma unroll
    for (int cc = 0; cc < 4; ++cc) {
        dO += o[cc] * wo2[cc];
#pragma unroll
        for (int k = 0; k < KC; ++k) {
            s[k]  += v[cc][k] * ws1[cc];   // selection score (sigmoid is monotone,
            d2[k] += v[cc][k] * ws2[cc];   //  orig-dot + b1 constant over k -> skip)
        }
    }

    // ---- butterfly reduce across the 4-lane point group ----
#pragma unroll
    for (int m = 1; m <= 2; m <<= 1) {
        dO += __shfl_xor(dO, m, 64);
#pragma unroll
        for (int k = 0; k < KC; ++k) {
            s[k]  += __shfl_xor(s[k],  m, 64);
            d2[k] += __shfl_xor(d2[k], m, 64);
        }
    }

    // ---- top-4 of 10 (ties -> lower index, matching lax.top_k) ----
    unsigned selmask = 0;
#pragma unroll
    for (int t4 = 0; t4 < KT; ++t4) {
        float best = -INFINITY;
        int bi = 0;
#pragma unroll
        for (int k = 0; k < KC; ++k) {
            const bool avail  = ((selmask >> k) & 1u) == 0u;
            const bool better = avail && (s[k] > best);
            best = better ? s[k] : best;
            bi   = better ? k : bi;
        }
        selmask |= (1u << bi);
    }

    // ---- recal weights: sigmoid(dot(orig,wo2) + dot(samp_k,ws2) + b2) ----
    float w[KC];
#pragma unroll
    for (int k = 0; k < KC; ++k) {
        const float x = dO + d2[k] + b2;
        const float sig = 1.f / (1.f + __expf(-x));
        w[k] = ((selmask >> k) & 1u) ? sig : 0.f;
    }

    // ---- weighted sum (register-resident features) + residual, store ----
#pragma unroll
    for (int cc = 0; cc < 4; ++cc) {
        float sum = 0.f;
#pragma unroll
        for (int k = 0; k < KC; ++k) sum += v[cc][k] * w[k];
        const int c = q * 4 + cc;
        const size_t base = (size_t)(b * CC + c) * NN + n;
        out[base] = o[cc] + sum;
    }
}

extern "C" void kernel_launch(void* const* d_in, const int* in_sizes, int n_in,
                              void* d_out, int out_size, void* d_ws, size_t ws_size,
                              hipStream_t stream) {
    const float* orig = (const float*)d_in[0];
    const float* samp = (const float*)d_in[1];
    const float* w1   = (const float*)d_in[2];
    // d_in[3] = b1 (unused: constant shift over k does not change top-k order)
    const float* w2   = (const float*)d_in[4];
    const float* b2   = (const float*)d_in[5];
    float* out = (float*)d_out;

    const int total_threads = BB * NN * 4;        // 4 lanes per point
    const int block = 256;
    const int grid = total_threads / block;       // 8192
    hipLaunchKernelGGL(swg_kernel, dim3(grid), dim3(block), 0, stream,
                       orig, samp, w1, w2, b2, out);
}

// Round 2
// 78.601 us; speedup vs baseline: 1.0694x; 1.0694x over previous
//
#include <hip/hip_runtime.h>
#include <math.h>

// Problem constants: B=8, C=16, N=65536, K_CAND=10, K_TOP=4
#define BB 8
#define CC 16
#define NN 65536
#define KC 10
#define KT 4

#define TPTS 64            // points per block
#define BLK  256           // threads per block (4 lanes per point)

// Stage sampled_features tile through LDS with fully-coalesced float4 loads,
// then compute with 4 lanes per point (4 channels per lane, register-resident
// v[4][10] reused for the weighted-sum pass).
__global__ __launch_bounds__(BLK) void swg_kernel(
    const float* __restrict__ orig,   // [B][C][N]
    const float* __restrict__ samp,   // [B][C][N][KC]
    const float* __restrict__ w1,     // [2C]
    const float* __restrict__ w2,     // [2C]
    const float* __restrict__ b2p,    // scalar
    float* __restrict__ out)          // [B][C][N]
{
    __shared__ float lds[CC * TPTS * KC];   // 16*64*10 = 10240 floats = 40 KB

    const int t = threadIdx.x;
    const int blk = blockIdx.x;
    const int p0 = blk * TPTS;              // first global point of tile
    const int b  = p0 >> 16;                // same b for whole tile (64 | 65536)
    const int n0 = p0 & (NN - 1);

    // ---- stage: thread t loads channel (t>>4), 10 float4 chunks, coalesced ----
    {
        const int sc = t >> 4;              // channel 0..15
        const int sl = t & 15;              // chunk lane 0..15
        const size_t gbase = ((size_t)(b * CC + sc) * NN + n0) * KC;
        const float4* g4 = (const float4*)(samp + gbase);   // n0 % 64 == 0 -> 16B aligned
        float4* l4 = (float4*)(lds + sc * (TPTS * KC));
#pragma unroll
        for (int j = 0; j < 10; ++j)
            l4[j * 16 + sl] = g4[j * 16 + sl];
    }
    __syncthreads();

    // ---- compute: 4 lanes per point ----
    const int q = t & 3;                    // channel group 0..3
    const int p = t >> 2;                   // local point 0..63
    const int n = n0 + p;

    const float b2 = b2p[0];

    float ws1[4], wo2[4], ws2[4];
#pragma unroll
    for (int cc = 0; cc < 4; ++cc) {
        const int c = q * 4 + cc;
        ws1[cc] = w1[CC + c];
        wo2[cc] = w2[c];
        ws2[cc] = w2[CC + c];
    }

    float v[4][KC];
    float o[4];
#pragma unroll
    for (int cc = 0; cc < 4; ++cc) {
        const int c = q * 4 + cc;
        const float2* lp = (const float2*)(lds + c * (TPTS * KC) + p * KC);
#pragma unroll
        for (int j = 0; j < 5; ++j) {
            const float2 x = lp[j];
            v[cc][2 * j]     = x.x;
            v[cc][2 * j + 1] = x.y;
        }
        o[cc] = orig[(size_t)(b * CC + c) * NN + n];
    }

    // ---- partial dots over this lane's 4 channels ----
    float s[KC], d2[KC];
    float dO = 0.f;
#pragma unroll
    for (int k = 0; k < KC; ++k) { s[k] = 0.f; d2[k] = 0.f; }
#pragma unroll
    for (int cc = 0; cc < 4; ++cc) {
        dO += o[cc] * wo2[cc];
#pragma unroll
        for (int k = 0; k < KC; ++k) {
            s[k]  += v[cc][k] * ws1[cc];   // selection score (sigmoid monotone,
            d2[k] += v[cc][k] * ws2[cc];   //  orig-dot + b1 constant over k)
        }
    }

    // ---- butterfly reduce across the 4-lane point group ----
#pragma unroll
    for (int m = 1; m <= 2; m <<= 1) {
        dO += __shfl_xor(dO, m, 64);
#pragma unroll
        for (int k = 0; k < KC; ++k) {
            s[k]  += __shfl_xor(s[k],  m, 64);
            d2[k] += __shfl_xor(d2[k], m, 64);
        }
    }

    // ---- top-4 of 10 (ties -> lower index, matching lax.top_k) ----
    unsigned selmask = 0;
#pragma unroll
    for (int t4 = 0; t4 < KT; ++t4) {
        float best = -INFINITY;
        int bi = 0;
#pragma unroll
        for (int k = 0; k < KC; ++k) {
            const bool avail  = ((selmask >> k) & 1u) == 0u;
            const bool better = avail && (s[k] > best);
            best = better ? s[k] : best;
            bi   = better ? k : bi;
        }
        selmask |= (1u << bi);
    }

    // ---- recal weights: sigmoid(dot(orig,wo2) + dot(samp_k,ws2) + b2) ----
    float w[KC];
#pragma unroll
    for (int k = 0; k < KC; ++k) {
        const float x = dO + d2[k] + b2;
        const float sig = 1.f / (1.f + __expf(-x));
        w[k] = ((selmask >> k) & 1u) ? sig : 0.f;
    }

    // ---- weighted sum (register-resident features) + residual, store ----
#pragma unroll
    for (int cc = 0; cc < 4; ++cc) {
        float sum = 0.f;
#pragma unroll
        for (int k = 0; k < KC; ++k) sum += v[cc][k] * w[k];
        const int c = q * 4 + cc;
        out[(size_t)(b * CC + c) * NN + n] = o[cc] + sum;
    }
}

extern "C" void kernel_launch(void* const* d_in, const int* in_sizes, int n_in,
                              void* d_out, int out_size, void* d_ws, size_t ws_size,
                              hipStream_t stream) {
    const float* orig = (const float*)d_in[0];
    const float* samp = (const float*)d_in[1];
    const float* w1   = (const float*)d_in[2];
    // d_in[3] = b1 (unused: constant shift over k does not change top-k order)
    const float* w2   = (const float*)d_in[4];
    const float* b2   = (const float*)d_in[5];
    float* out = (float*)d_out;

    const int grid = (BB * NN) / TPTS;    // 8192 blocks
    hipLaunchKernelGGL(swg_kernel, dim3(grid), dim3(BLK), 0, stream,
                       orig, samp, w1, w2, b2, out);
}

// Round 3
// 78.396 us; speedup vs baseline: 1.0722x; 1.0026x over previous
//
#include <hip/hip_runtime.h>
#include <math.h>

// Problem constants: B=8, C=16, N=65536, K_CAND=10, K_TOP=4
#define BB 8
#define CC 16
#define NN 65536
#define KC 10
#define KT 4

#define TPTS 64            // points per block
#define BLK  256           // threads per block (4 lanes per point)

// Stage sampled_features tile through LDS with fully-coalesced float4 loads,
// then compute with 4 lanes per point (4 channels per lane, register-resident
// v[4][10] reused for the weighted-sum pass). Selection via rank counting,
// sigmoid via hardware rcp.
__global__ __launch_bounds__(BLK) void swg_kernel(
    const float* __restrict__ orig,   // [B][C][N]
    const float* __restrict__ samp,   // [B][C][N][KC]
    const float* __restrict__ w1,     // [2C]
    const float* __restrict__ w2,     // [2C]
    const float* __restrict__ b2p,    // scalar
    float* __restrict__ out)          // [B][C][N]
{
    __shared__ float lds[CC * TPTS * KC];   // 16*64*10 = 10240 floats = 40 KB

    const int t = threadIdx.x;
    const int blk = blockIdx.x;
    const int p0 = blk * TPTS;              // first global point of tile
    const int b  = p0 >> 16;                // same b for whole tile (64 | 65536)
    const int n0 = p0 & (NN - 1);

    // ---- compute-side ids ----
    const int q = t & 3;                    // channel group 0..3
    const int p = t >> 2;                   // local point 0..63
    const int n = n0 + p;

    // ---- issue orig loads early (independent of LDS staging) ----
    float o[4];
#pragma unroll
    for (int cc = 0; cc < 4; ++cc) {
        const int c = q * 4 + cc;
        o[cc] = orig[(size_t)(b * CC + c) * NN + n];
    }

    // ---- stage: thread t loads channel (t>>4), 10 float4 chunks, coalesced ----
    {
        const int sc = t >> 4;              // channel 0..15
        const int sl = t & 15;              // chunk lane 0..15
        const size_t gbase = ((size_t)(b * CC + sc) * NN + n0) * KC;
        const float4* g4 = (const float4*)(samp + gbase);   // n0 % 64 == 0 -> 16B aligned
        float4* l4 = (float4*)(lds + sc * (TPTS * KC));
#pragma unroll
        for (int j = 0; j < 10; ++j)
            l4[j * 16 + sl] = g4[j * 16 + sl];
    }
    __syncthreads();

    const float b2 = b2p[0];

    float ws1[4], wo2[4], ws2[4];
#pragma unroll
    for (int cc = 0; cc < 4; ++cc) {
        const int c = q * 4 + cc;
        ws1[cc] = w1[CC + c];
        wo2[cc] = w2[c];
        ws2[cc] = w2[CC + c];
    }

    float v[4][KC];
#pragma unroll
    for (int cc = 0; cc < 4; ++cc) {
        const int c = q * 4 + cc;
        const float2* lp = (const float2*)(lds + c * (TPTS * KC) + p * KC);
#pragma unroll
        for (int j = 0; j < 5; ++j) {
            const float2 x = lp[j];
            v[cc][2 * j]     = x.x;
            v[cc][2 * j + 1] = x.y;
        }
    }

    // ---- partial dots over this lane's 4 channels ----
    float s[KC], d2[KC];
    float dO = 0.f;
#pragma unroll
    for (int k = 0; k < KC; ++k) { s[k] = 0.f; d2[k] = 0.f; }
#pragma unroll
    for (int cc = 0; cc < 4; ++cc) {
        dO += o[cc] * wo2[cc];
#pragma unroll
        for (int k = 0; k < KC; ++k) {
            s[k]  += v[cc][k] * ws1[cc];   // selection score (sigmoid monotone,
            d2[k] += v[cc][k] * ws2[cc];   //  orig-dot + b1 constant over k)
        }
    }

    // ---- butterfly reduce across the 4-lane point group ----
#pragma unroll
    for (int m = 1; m <= 2; m <<= 1) {
        dO += __shfl_xor(dO, m, 64);
#pragma unroll
        for (int k = 0; k < KC; ++k) {
            s[k]  += __shfl_xor(s[k],  m, 64);
            d2[k] += __shfl_xor(d2[k], m, 64);
        }
    }

    // ---- selection by rank counting: k selected iff rank[k] < 4.
    //      beats(j,k) for j<k uses >=, reproducing lax.top_k's lower-index
    //      tie-break; output depends only on the selected SET. ----
    int rank[KC];
#pragma unroll
    for (int k = 0; k < KC; ++k) rank[k] = 0;
#pragma unroll
    for (int j = 0; j < KC; ++j) {
#pragma unroll
        for (int k = j + 1; k < KC; ++k) {
            const bool jge = s[j] >= s[k];
            rank[k] += jge ? 1 : 0;
            rank[j] += jge ? 0 : 1;
        }
    }

    // ---- recal weights: sigmoid via hw rcp (abs tolerance 0.18 >> rcp err) ----
    float w[KC];
#pragma unroll
    for (int k = 0; k < KC; ++k) {
        const float x = dO + d2[k] + b2;
        const float sig = __builtin_amdgcn_rcpf(1.f + __expf(-x));
        w[k] = (rank[k] < KT) ? sig : 0.f;
    }

    // ---- weighted sum (register-resident features) + residual, store ----
#pragma unroll
    for (int cc = 0; cc < 4; ++cc) {
        float sum = 0.f;
#pragma unroll
        for (int k = 0; k < KC; ++k) sum += v[cc][k] * w[k];
        const int c = q * 4 + cc;
        out[(size_t)(b * CC + c) * NN + n] = o[cc] + sum;
    }
}

extern "C" void kernel_launch(void* const* d_in, const int* in_sizes, int n_in,
                              void* d_out, int out_size, void* d_ws, size_t ws_size,
                              hipStream_t stream) {
    const float* orig = (const float*)d_in[0];
    const float* samp = (const float*)d_in[1];
    const float* w1   = (const float*)d_in[2];
    // d_in[3] = b1 (unused: constant shift over k does not change top-k order)
    const float* w2   = (const float*)d_in[4];
    const float* b2   = (const float*)d_in[5];
    float* out = (float*)d_out;

    const int grid = (BB * NN) / TPTS;    // 8192 blocks
    hipLaunchKernelGGL(swg_kernel, dim3(grid), dim3(BLK), 0, stream,
                       orig, samp, w1, w2, b2, out);
}